// Round 2
// baseline (992.867 us; speedup 1.0000x reference)
//
#include <hip/hip_runtime.h>
#include <hip/hip_bf16.h>

typedef __bf16 bf16;
typedef __attribute__((ext_vector_type(8))) __bf16 bf16x8;
typedef __attribute__((ext_vector_type(4))) float f32x4;

constexpr int D_IN  = 512;
constexpr int D_HID = 256;
constexpr int D_OUT = 32;
constexpr int BM = 64;     // rows per block
constexpr int BK = 32;     // K chunk (one 16x16x32 MFMA deep)
constexpr int HPAD = 264;  // 256 + 8 bf16 pad: breaks 512B-stride bank conflicts

// ---------------- prep: W1 -> W1T (bf16, [n][k]), W2 -> W2T (bf16, [n][k]) --
__global__ __launch_bounds__(256) void prep_kernel(
    const float* __restrict__ W1, const float* __restrict__ W2,
    bf16* __restrict__ W1T, bf16* __restrict__ W2T)
{
    int idx = blockIdx.x * 256 + threadIdx.x;
    if (idx < D_IN * D_HID) {
        int k = idx / D_HID, n = idx % D_HID;
        W1T[n * D_IN + k] = (bf16)W1[idx];
    }
    int j = idx - D_IN * D_HID;
    if (j >= 0 && j < D_HID * D_OUT) {
        int k = j / D_OUT, n = j % D_OUT;
        W2T[n * D_HID + k] = (bf16)W2[j];
    }
}

// ---------------- fused MLP: X = relu(feat@W1 + b1) @ W2 + b2 ---------------
__global__ __launch_bounds__(256) void fused_mlp_kernel(
    const float* __restrict__ feat,
    const bf16* __restrict__ W1T, const bf16* __restrict__ W2T,
    const float* __restrict__ b1, const float* __restrict__ b2,
    float* __restrict__ X, int N)
{
    __shared__ __align__(16) bf16 Asm[BM * BK];          // [m][k]  4 KB
    __shared__ __align__(16) bf16 Bsm[D_HID * BK];       // [n][k] 16 KB
    __shared__ __align__(16) bf16 Hsm[BM * HPAD];        // [m][k] ~33 KB
    __shared__ __align__(16) bf16 B2sm[D_OUT * HPAD];    // [n][k] ~16.5 KB

    const int tid  = threadIdx.x;
    const int wave = tid >> 6;
    const int lane = tid & 63;
    const int ln   = lane & 15;   // MFMA row/col index
    const int q    = lane >> 4;   // quad 0..3
    const int mw   = wave * 16;   // wave's row block within tile
    const int r0   = blockIdx.x * BM;

    // Stage W2T -> B2sm once: 32 rows x 256 bf16 = 1024 x 16B chunks, 4/thread
    #pragma unroll
    for (int i = 0; i < 4; ++i) {
        int c  = tid + i * 256;        // chunk id 0..1023
        int n  = c >> 5;               // 32 chunks per n-row -> n 0..31
        int kc = (c & 31) * 8;
        *(bf16x8*)&B2sm[n * HPAD + kc] = *(const bf16x8*)&W2T[n * D_HID + kc];
    }

    f32x4 acc[16] = {};  // 16 n-tiles of 16x16 per wave (full D_HID)

    // A staging assignment: thread -> (row am, 8-wide k slice asub)
    const int am   = tid >> 2;           // 0..63
    const int asub = (tid & 3) * 8;      // 0,8,16,24
    const long arow = (long)min(r0 + am, N - 1);
    const float* asrc = feat + arow * D_IN + asub;

    for (int k0 = 0; k0 < D_IN; k0 += BK) {
        // stage A chunk (fp32 -> bf16 in-register)
        float4 f0 = *(const float4*)(asrc + k0);
        float4 f1 = *(const float4*)(asrc + k0 + 4);
        bf16x8 av;
        av[0] = (bf16)f0.x; av[1] = (bf16)f0.y; av[2] = (bf16)f0.z; av[3] = (bf16)f0.w;
        av[4] = (bf16)f1.x; av[5] = (bf16)f1.y; av[6] = (bf16)f1.z; av[7] = (bf16)f1.w;
        *(bf16x8*)&Asm[am * BK + asub] = av;

        // stage B chunk from W1T: 256 rows x 32 bf16 = 1024 x 16B chunks, 4/thread
        #pragma unroll
        for (int i = 0; i < 4; ++i) {
            int c   = tid + i * 256;      // chunk id 0..1023
            int n   = c >> 2;             // 4 chunks per n-row -> n 0..255
            int kc8 = (c & 3) * 8;
            *(bf16x8*)&Bsm[n * BK + kc8] =
                *(const bf16x8*)&W1T[n * D_IN + k0 + kc8];
        }
        __syncthreads();

        bf16x8 af = *(const bf16x8*)&Asm[(mw + ln) * BK + q * 8];
        #pragma unroll
        for (int t = 0; t < 16; ++t) {
            bf16x8 bf = *(const bf16x8*)&Bsm[(t * 16 + ln) * BK + q * 8];
            acc[t] = __builtin_amdgcn_mfma_f32_16x16x32_bf16(af, bf, acc[t], 0, 0, 0);
        }
        __syncthreads();
    }

    // Epilogue 1: h = relu(acc + b1) -> Hsm (bf16, A-operand layout for GEMM2)
    #pragma unroll
    for (int t = 0; t < 16; ++t) {
        int colh = t * 16 + ln;
        float bb = b1[colh];
        #pragma unroll
        for (int i = 0; i < 4; ++i) {
            int row = mw + q * 4 + i;
            float v = acc[t][i] + bb;
            Hsm[row * HPAD + colh] = (bf16)fmaxf(v, 0.0f);
        }
    }
    __syncthreads();

    // GEMM2: X_tile = Hsm @ W2 (K=256, N=32) — 2 n-tiles per wave
    f32x4 acc2[2] = {};
    #pragma unroll
    for (int k0 = 0; k0 < D_HID; k0 += BK) {
        bf16x8 af = *(const bf16x8*)&Hsm[(mw + ln) * HPAD + k0 + q * 8];
        #pragma unroll
        for (int t = 0; t < 2; ++t) {
            bf16x8 bf = *(const bf16x8*)&B2sm[(t * 16 + ln) * HPAD + k0 + q * 8];
            acc2[t] = __builtin_amdgcn_mfma_f32_16x16x32_bf16(af, bf, acc2[t], 0, 0, 0);
        }
    }

    // Epilogue 2: X = acc2 + b2 (fp32)
    #pragma unroll
    for (int t = 0; t < 2; ++t) {
        int c = t * 16 + ln;
        float bb = b2[c];
        #pragma unroll
        for (int i = 0; i < 4; ++i) {
            int row = r0 + mw + q * 4 + i;
            if (row < N) X[row * D_OUT + c] = acc2[t][i] + bb;
        }
    }
}

// ---------------- scatter: out[row] += A_data[e] * X[col] -------------------
__global__ __launch_bounds__(256) void scatter_kernel(
    const float* __restrict__ Adata, const int* __restrict__ Arow,
    const int* __restrict__ Acol, const float* __restrict__ X,
    float* __restrict__ out, int E)
{
    int idx = blockIdx.x * 256 + threadIdx.x;
    int e = idx >> 3;        // 8 threads per edge
    int g = idx & 7;         // 4-dim group
    if (e >= E) return;
    int   col = Acol[e];
    int   row = Arow[e];
    float a   = Adata[e];
    float4 x = *(const float4*)(X + (long)col * D_OUT + g * 4);
    float* o = out + (long)row * D_OUT + g * 4;
    unsafeAtomicAdd(o + 0, a * x.x);
    unsafeAtomicAdd(o + 1, a * x.y);
    unsafeAtomicAdd(o + 2, a * x.z);
    unsafeAtomicAdd(o + 3, a * x.w);
}

// ---------------- launch ----------------------------------------------------
extern "C" void kernel_launch(void* const* d_in, const int* in_sizes, int n_in,
                              void* d_out, int out_size, void* d_ws, size_t ws_size,
                              hipStream_t stream)
{
    const float* feat  = (const float*)d_in[0];
    const float* Adata = (const float*)d_in[1];
    const float* W1    = (const float*)d_in[2];
    const float* b1    = (const float*)d_in[3];
    const float* W2    = (const float*)d_in[4];
    const float* b2    = (const float*)d_in[5];
    const int*   Arow  = (const int*)d_in[6];
    const int*   Acol  = (const int*)d_in[7];

    const int N = in_sizes[0] / D_IN;
    const int E = in_sizes[1];

    // workspace layout: X [N*32 f32] | W1T [256*512 bf16] | W2T [32*256 bf16]
    float* X   = (float*)d_ws;
    bf16* W1T  = (bf16*)((char*)d_ws + (size_t)N * D_OUT * sizeof(float));
    bf16* W2T  = W1T + D_IN * D_HID;
    float* out = (float*)d_out;

    hipMemsetAsync(out, 0, (size_t)out_size * sizeof(float), stream);

    int prep_elems = D_IN * D_HID + D_HID * D_OUT;
    prep_kernel<<<(prep_elems + 255) / 256, 256, 0, stream>>>(W1, W2, W1T, W2T);

    fused_mlp_kernel<<<(N + BM - 1) / BM, 256, 0, stream>>>(
        feat, W1T, W2T, b1, b2, X, N);

    long scatter_threads = (long)E * 8;
    scatter_kernel<<<(scatter_threads + 255) / 256, 256, 0, stream>>>(
        Adata, Arow, Acol, X, out, E);
}

// Round 3
// 576.248 us; speedup vs baseline: 1.7230x; 1.7230x over previous
//
#include <hip/hip_runtime.h>
#include <hip/hip_bf16.h>

typedef __bf16 bf16;
typedef __attribute__((ext_vector_type(8))) __bf16 bf16x8;
typedef __attribute__((ext_vector_type(4))) float f32x4;

constexpr int D_IN  = 512;
constexpr int D_HID = 256;
constexpr int D_OUT = 32;
constexpr int BM = 64;     // rows per block
constexpr int BK = 32;     // K chunk (one 16x16x32 MFMA deep)
constexpr int HPAD = 264;  // 256 + 8 bf16 pad: breaks 512B-stride bank conflicts
constexpr int SCAN_VPT  = 8;
constexpr int SCAN_SPAN = 2048;  // 256 threads * 8

// ---------------- prep: W1 -> W1T (bf16, [n][k]), W2 -> W2T (bf16, [n][k]) --
__global__ __launch_bounds__(256) void prep_kernel(
    const float* __restrict__ W1, const float* __restrict__ W2,
    bf16* __restrict__ W1T, bf16* __restrict__ W2T)
{
    int idx = blockIdx.x * 256 + threadIdx.x;
    if (idx < D_IN * D_HID) {
        int k = idx / D_HID, n = idx % D_HID;
        W1T[n * D_IN + k] = (bf16)W1[idx];
    }
    int j = idx - D_IN * D_HID;
    if (j >= 0 && j < D_HID * D_OUT) {
        int k = j / D_OUT, n = j % D_OUT;
        W2T[n * D_HID + k] = (bf16)W2[j];
    }
}

// ---------------- fused MLP: X = relu(feat@W1 + b1) @ W2 + b2 ---------------
__global__ __launch_bounds__(256) void fused_mlp_kernel(
    const float* __restrict__ feat,
    const bf16* __restrict__ W1T, const bf16* __restrict__ W2T,
    const float* __restrict__ b1, const float* __restrict__ b2,
    float* __restrict__ X, int N)
{
    __shared__ __align__(16) bf16 Asm[BM * BK];          // [m][k]  4 KB
    __shared__ __align__(16) bf16 Bsm[D_HID * BK];       // [n][k] 16 KB
    __shared__ __align__(16) bf16 Hsm[BM * HPAD];        // [m][k] ~33 KB
    __shared__ __align__(16) bf16 B2sm[D_OUT * HPAD];    // [n][k] ~16.5 KB

    const int tid  = threadIdx.x;
    const int wave = tid >> 6;
    const int lane = tid & 63;
    const int ln   = lane & 15;   // MFMA row/col index
    const int q    = lane >> 4;   // quad 0..3
    const int mw   = wave * 16;   // wave's row block within tile
    const int r0   = blockIdx.x * BM;

    // Stage W2T -> B2sm once: 32 rows x 256 bf16 = 1024 x 16B chunks, 4/thread
    #pragma unroll
    for (int i = 0; i < 4; ++i) {
        int c  = tid + i * 256;        // chunk id 0..1023
        int n  = c >> 5;               // 32 chunks per n-row -> n 0..31
        int kc = (c & 31) * 8;
        *(bf16x8*)&B2sm[n * HPAD + kc] = *(const bf16x8*)&W2T[n * D_HID + kc];
    }

    f32x4 acc[16] = {};  // 16 n-tiles of 16x16 per wave (full D_HID)

    // A staging assignment: thread -> (row am, 8-wide k slice asub)
    const int am   = tid >> 2;           // 0..63
    const int asub = (tid & 3) * 8;      // 0,8,16,24
    const long arow = (long)min(r0 + am, N - 1);
    const float* asrc = feat + arow * D_IN + asub;

    for (int k0 = 0; k0 < D_IN; k0 += BK) {
        // stage A chunk (fp32 -> bf16 in-register)
        float4 f0 = *(const float4*)(asrc + k0);
        float4 f1 = *(const float4*)(asrc + k0 + 4);
        bf16x8 av;
        av[0] = (bf16)f0.x; av[1] = (bf16)f0.y; av[2] = (bf16)f0.z; av[3] = (bf16)f0.w;
        av[4] = (bf16)f1.x; av[5] = (bf16)f1.y; av[6] = (bf16)f1.z; av[7] = (bf16)f1.w;
        *(bf16x8*)&Asm[am * BK + asub] = av;

        // stage B chunk from W1T: 256 rows x 32 bf16 = 1024 x 16B chunks, 4/thread
        #pragma unroll
        for (int i = 0; i < 4; ++i) {
            int c   = tid + i * 256;      // chunk id 0..1023
            int n   = c >> 2;             // 4 chunks per n-row -> n 0..255
            int kc8 = (c & 3) * 8;
            *(bf16x8*)&Bsm[n * BK + kc8] =
                *(const bf16x8*)&W1T[n * D_IN + k0 + kc8];
        }
        __syncthreads();

        bf16x8 af = *(const bf16x8*)&Asm[(mw + ln) * BK + q * 8];
        #pragma unroll
        for (int t = 0; t < 16; ++t) {
            bf16x8 bf = *(const bf16x8*)&Bsm[(t * 16 + ln) * BK + q * 8];
            acc[t] = __builtin_amdgcn_mfma_f32_16x16x32_bf16(af, bf, acc[t], 0, 0, 0);
        }
        __syncthreads();
    }

    // Epilogue 1: h = relu(acc + b1) -> Hsm (bf16, A-operand layout for GEMM2)
    #pragma unroll
    for (int t = 0; t < 16; ++t) {
        int colh = t * 16 + ln;
        float bb = b1[colh];
        #pragma unroll
        for (int i = 0; i < 4; ++i) {
            int row = mw + q * 4 + i;
            float v = acc[t][i] + bb;
            Hsm[row * HPAD + colh] = (bf16)fmaxf(v, 0.0f);
        }
    }
    __syncthreads();

    // GEMM2: X_tile = Hsm @ W2 (K=256, N=32) — 2 n-tiles per wave
    f32x4 acc2[2] = {};
    #pragma unroll
    for (int k0 = 0; k0 < D_HID; k0 += BK) {
        bf16x8 af = *(const bf16x8*)&Hsm[(mw + ln) * HPAD + k0 + q * 8];
        #pragma unroll
        for (int t = 0; t < 2; ++t) {
            bf16x8 bf = *(const bf16x8*)&B2sm[(t * 16 + ln) * HPAD + k0 + q * 8];
            acc2[t] = __builtin_amdgcn_mfma_f32_16x16x32_bf16(af, bf, acc2[t], 0, 0, 0);
        }
    }

    // Epilogue 2: X = acc2 + b2 (fp32)
    #pragma unroll
    for (int t = 0; t < 2; ++t) {
        int c = t * 16 + ln;
        float bb = b2[c];
        #pragma unroll
        for (int i = 0; i < 4; ++i) {
            int row = r0 + mw + q * 4 + i;
            if (row < N) X[row * D_OUT + c] = acc2[t][i] + bb;
        }
    }
}

// ---------------- CSR build: histogram -> scan -> reorder -------------------
__global__ __launch_bounds__(256) void hist_kernel(
    const int* __restrict__ Arow, int* __restrict__ counts, int E)
{
    int e = blockIdx.x * 256 + threadIdx.x;
    if (e < E) atomicAdd(&counts[Arow[e]], 1);
}

// per-block exclusive scan over SCAN_SPAN elements; block totals -> partials
__global__ __launch_bounds__(256) void scanA_kernel(
    const int* __restrict__ counts, int* __restrict__ offs,
    int* __restrict__ partials, int N)
{
    __shared__ int lds[256];
    int t = threadIdx.x;
    int base = blockIdx.x * SCAN_SPAN + t * SCAN_VPT;
    int v[SCAN_VPT];
    int tsum = 0;
    #pragma unroll
    for (int j = 0; j < SCAN_VPT; ++j) {
        v[j] = (base + j < N) ? counts[base + j] : 0;
        tsum += v[j];
    }
    lds[t] = tsum;
    __syncthreads();
    // inclusive Hillis-Steele scan over 256 thread sums
    for (int d = 1; d < 256; d <<= 1) {
        int x = (t >= d) ? lds[t - d] : 0;
        __syncthreads();
        lds[t] += x;
        __syncthreads();
    }
    int run = lds[t] - tsum;  // exclusive offset of this thread's chunk
    #pragma unroll
    for (int j = 0; j < SCAN_VPT; ++j) {
        if (base + j < N) offs[base + j] = run;
        run += v[j];
    }
    if (t == 255) partials[blockIdx.x] = lds[255];
}

// single block: exclusive scan of block partials (nb <= 256)
__global__ __launch_bounds__(256) void scanB_kernel(int* __restrict__ partials, int nb)
{
    __shared__ int lds[256];
    int t = threadIdx.x;
    int v = (t < nb) ? partials[t] : 0;
    lds[t] = v;
    __syncthreads();
    for (int d = 1; d < 256; d <<= 1) {
        int x = (t >= d) ? lds[t - d] : 0;
        __syncthreads();
        lds[t] += x;
        __syncthreads();
    }
    if (t < nb) partials[t] = lds[t] - v;
}

// add scanned block bases; init per-row cursor
__global__ __launch_bounds__(256) void scanC_kernel(
    int* __restrict__ offs, const int* __restrict__ partials,
    int* __restrict__ cursor, int N)
{
    int i = blockIdx.x * 256 + threadIdx.x;
    if (i < N) {
        int o = offs[i] + partials[i / SCAN_SPAN];
        offs[i] = o;
        cursor[i] = o;
    }
}

__global__ __launch_bounds__(256) void reorder_kernel(
    const int* __restrict__ Arow, const int* __restrict__ Acol,
    const float* __restrict__ Adata, int* __restrict__ cursor,
    int* __restrict__ col_s, float* __restrict__ a_s, int E)
{
    int e = blockIdx.x * 256 + threadIdx.x;
    if (e >= E) return;
    int r = Arow[e];
    int p = atomicAdd(&cursor[r], 1);
    col_s[p] = Acol[e];
    a_s[p]   = Adata[e];
}

// ---------------- reduce: one wave per row, no atomics ----------------------
__global__ __launch_bounds__(256) void reduce_kernel(
    const int* __restrict__ offs, const int* __restrict__ counts,
    const int* __restrict__ col_s, const float* __restrict__ a_s,
    const float* __restrict__ X, float* __restrict__ out, int N)
{
    int w    = threadIdx.x >> 6;
    int lane = threadIdx.x & 63;
    int r    = blockIdx.x * 4 + w;
    if (r >= N) return;
    int half = lane >> 5;   // which edge of the pair
    int dim  = lane & 31;   // output dim
    int off  = offs[r];
    int deg  = counts[r];
    float acc = 0.0f;
    int i = half;
    // 2 edges in flight per half-wave pair; unroll x2 for ILP
    for (; i + 2 < deg; i += 4) {
        int   c0 = col_s[off + i];
        float a0 = a_s[off + i];
        int   c1 = col_s[off + i + 2];
        float a1 = a_s[off + i + 2];
        acc += a0 * X[(long)c0 * D_OUT + dim];
        acc += a1 * X[(long)c1 * D_OUT + dim];
    }
    for (; i < deg; i += 2) {
        int   c = col_s[off + i];
        float a = a_s[off + i];
        acc += a * X[(long)c * D_OUT + dim];
    }
    acc += __shfl_xor(acc, 32, 64);
    if (!half) out[(long)r * D_OUT + dim] = acc;
}

// ---------------- fallback scatter (if ws too small) ------------------------
__global__ __launch_bounds__(256) void scatter_kernel(
    const float* __restrict__ Adata, const int* __restrict__ Arow,
    const int* __restrict__ Acol, const float* __restrict__ X,
    float* __restrict__ out, int E)
{
    int idx = blockIdx.x * 256 + threadIdx.x;
    int e = idx >> 3;
    int g = idx & 7;
    if (e >= E) return;
    int   col = Acol[e];
    int   row = Arow[e];
    float a   = Adata[e];
    float4 x = *(const float4*)(X + (long)col * D_OUT + g * 4);
    float* o = out + (long)row * D_OUT + g * 4;
    unsafeAtomicAdd(o + 0, a * x.x);
    unsafeAtomicAdd(o + 1, a * x.y);
    unsafeAtomicAdd(o + 2, a * x.z);
    unsafeAtomicAdd(o + 3, a * x.w);
}

// ---------------- launch ----------------------------------------------------
extern "C" void kernel_launch(void* const* d_in, const int* in_sizes, int n_in,
                              void* d_out, int out_size, void* d_ws, size_t ws_size,
                              hipStream_t stream)
{
    const float* feat  = (const float*)d_in[0];
    const float* Adata = (const float*)d_in[1];
    const float* W1    = (const float*)d_in[2];
    const float* b1    = (const float*)d_in[3];
    const float* W2    = (const float*)d_in[4];
    const float* b2    = (const float*)d_in[5];
    const int*   Arow  = (const int*)d_in[6];
    const int*   Acol  = (const int*)d_in[7];

    const int N = in_sizes[0] / D_IN;
    const int E = in_sizes[1];

    // --- workspace carve-out (256B aligned segments) ---
    char* p = (char*)d_ws;
    auto alloc = [&](size_t bytes) {
        char* q = p;
        p += (bytes + 255) & ~(size_t)255;
        return q;
    };
    float* X       = (float*)alloc((size_t)N * D_OUT * sizeof(float));
    bf16*  W1T     = (bf16*) alloc((size_t)D_IN * D_HID * sizeof(bf16));
    bf16*  W2T     = (bf16*) alloc((size_t)D_HID * D_OUT * sizeof(bf16));
    int*   counts  = (int*)  alloc((size_t)N * sizeof(int));
    int*   offs    = (int*)  alloc((size_t)N * sizeof(int));
    int*   cursor  = (int*)  alloc((size_t)N * sizeof(int));
    int*   partials= (int*)  alloc(256 * sizeof(int));
    int*   col_s   = (int*)  alloc((size_t)E * sizeof(int));
    float* a_s     = (float*)alloc((size_t)E * sizeof(float));
    size_t need = (size_t)(p - (char*)d_ws);
    const bool use_csr = (need <= ws_size);

    float* out = (float*)d_out;

    int prep_elems = D_IN * D_HID + D_HID * D_OUT;
    prep_kernel<<<(prep_elems + 255) / 256, 256, 0, stream>>>(W1, W2, W1T, W2T);

    fused_mlp_kernel<<<(N + BM - 1) / BM, 256, 0, stream>>>(
        feat, W1T, W2T, b1, b2, X, N);

    if (use_csr) {
        hipMemsetAsync(counts, 0, (size_t)N * sizeof(int), stream);
        hist_kernel<<<(E + 255) / 256, 256, 0, stream>>>(Arow, counts, E);
        int nb = (N + SCAN_SPAN - 1) / SCAN_SPAN;   // 49 for N=100000 (<=256)
        scanA_kernel<<<nb, 256, 0, stream>>>(counts, offs, partials, N);
        scanB_kernel<<<1, 256, 0, stream>>>(partials, nb);
        scanC_kernel<<<(N + 255) / 256, 256, 0, stream>>>(offs, partials, cursor, N);
        reorder_kernel<<<(E + 255) / 256, 256, 0, stream>>>(
            Arow, Acol, Adata, cursor, col_s, a_s, E);
        reduce_kernel<<<(N + 3) / 4, 256, 0, stream>>>(
            offs, counts, col_s, a_s, X, out, N);
    } else {
        hipMemsetAsync(out, 0, (size_t)out_size * sizeof(float), stream);
        long scatter_threads = (long)E * 8;
        scatter_kernel<<<(scatter_threads + 255) / 256, 256, 0, stream>>>(
            Adata, Arow, Acol, X, out, E);
    }
}

// Round 4
// 574.582 us; speedup vs baseline: 1.7280x; 1.0029x over previous
//
#include <hip/hip_runtime.h>
#include <hip/hip_bf16.h>

typedef __bf16 bf16;
typedef __attribute__((ext_vector_type(8))) __bf16 bf16x8;
typedef __attribute__((ext_vector_type(4))) float f32x4;

constexpr int D_IN  = 512;
constexpr int D_HID = 256;
constexpr int D_OUT = 32;
constexpr int BM = 64;     // rows per block
constexpr int BK = 32;     // K chunk (one 16x16x32 MFMA deep)
constexpr int HPAD = 260;  // stride 260 bf16 = 130 dwords = 2 mod 32:
                           // epilogue-1 scalar writes land on 32 distinct banks,
                           // frag b128 reads stay at the uniform 8-lanes/bank min
constexpr int SCAN_VPT  = 8;
constexpr int SCAN_SPAN = 2048;  // 256 threads * 8

#define GLOBAL_AS(p) ((const __attribute__((address_space(1))) void*)(p))
#define LDS_AS(p)    ((__attribute__((address_space(3))) void*)(p))

// ---------------- prep: W1 -> W1T (bf16, [n][k]), W2 -> W2T (bf16, [n][k]) --
__global__ __launch_bounds__(256) void prep_kernel(
    const float* __restrict__ W1, const float* __restrict__ W2,
    bf16* __restrict__ W1T, bf16* __restrict__ W2T)
{
    int idx = blockIdx.x * 256 + threadIdx.x;
    if (idx < D_IN * D_HID) {
        int k = idx / D_HID, n = idx % D_HID;
        W1T[n * D_IN + k] = (bf16)W1[idx];
    }
    int j = idx - D_IN * D_HID;
    if (j >= 0 && j < D_HID * D_OUT) {
        int k = j / D_OUT, n = j % D_OUT;
        W2T[n * D_HID + k] = (bf16)W2[j];
    }
}

// ---------------- fused MLP: X = relu(feat@W1 + b1) @ W2 + b2 ---------------
__global__ __launch_bounds__(256) void fused_mlp_kernel(
    const float* __restrict__ feat,
    const bf16* __restrict__ W1T, const bf16* __restrict__ W2T,
    const float* __restrict__ b1, const float* __restrict__ b2,
    float* __restrict__ X, int N)
{
    // Hsm aliases (Asm | Bsm): staging is dead once the K-loop finishes.
    // layout: [0, 4096)  Asm        [4096, 20480) Bsm
    //         [0, 33280) Hsm (overlap, used after K-loop)
    //         [33280, 49920) B2sm
    __shared__ __align__(16) char smem[(BM + D_OUT) * HPAD * sizeof(bf16)];
    bf16* Asm  = (bf16*)smem;                         // [BM][BK]
    bf16* Bsm  = (bf16*)(smem + BM * BK * 2);         // [D_HID][BK]
    bf16* Hsm  = (bf16*)smem;                         // [BM][HPAD]
    bf16* B2sm = (bf16*)(smem + BM * HPAD * 2);       // [D_OUT][HPAD]

    const int tid  = threadIdx.x;
    const int wave = tid >> 6;
    const int lane = tid & 63;
    const int ln   = lane & 15;   // MFMA row/col index
    const int q    = lane >> 4;   // quad 0..3
    const int mw   = wave * 16;   // wave's row block within tile
    const int r0   = blockIdx.x * BM;

    // Stage W2T -> B2sm once: 32 rows x 256 bf16 = 1024 x 16B chunks, 4/thread
    #pragma unroll
    for (int i = 0; i < 4; ++i) {
        int c  = tid + i * 256;        // chunk id 0..1023
        int n  = c >> 5;               // 32 chunks per n-row -> n 0..31
        int kc = (c & 31) * 8;
        *(bf16x8*)&B2sm[n * HPAD + kc] = *(const bf16x8*)&W2T[n * D_HID + kc];
    }

    f32x4 acc[16] = {};  // 16 n-tiles of 16x16 per wave (full D_HID)

    // A staging assignment: thread -> (row am, 8-wide k slice asub)
    const int am   = tid >> 2;           // 0..63
    const int asub = (tid & 3) * 8;      // 0,8,16,24
    const long arow = (long)min(r0 + am, N - 1);
    const float* asrc = feat + arow * D_IN + asub;

    for (int k0 = 0; k0 < D_IN; k0 += BK) {
        // async stage B chunk from W1T: chunk c = i*256 + wave*64 + lane lands
        // at LDS byte 16*c (lane-contiguous); base is wave-uniform.
        #pragma unroll
        for (int i = 0; i < 4; ++i) {
            int c = i * 256 + wave * 64 + lane;
            const bf16* gsrc = W1T + ((c >> 2) * D_IN + k0 + (c & 3) * 8);
            bf16* lbase = Bsm + (i * 256 + wave * 64) * 8;  // wave-uniform
            __builtin_amdgcn_global_load_lds(GLOBAL_AS(gsrc), LDS_AS(lbase), 16, 0, 0);
        }

        // stage A chunk (fp32 -> bf16 in-register)
        float4 f0 = *(const float4*)(asrc + k0);
        float4 f1 = *(const float4*)(asrc + k0 + 4);
        bf16x8 av;
        av[0] = (bf16)f0.x; av[1] = (bf16)f0.y; av[2] = (bf16)f0.z; av[3] = (bf16)f0.w;
        av[4] = (bf16)f1.x; av[5] = (bf16)f1.y; av[6] = (bf16)f1.z; av[7] = (bf16)f1.w;
        *(bf16x8*)&Asm[am * BK + asub] = av;

        __syncthreads();

        bf16x8 af = *(const bf16x8*)&Asm[(mw + ln) * BK + q * 8];
        #pragma unroll
        for (int t = 0; t < 16; ++t) {
            bf16x8 bf = *(const bf16x8*)&Bsm[(t * 16 + ln) * BK + q * 8];
            acc[t] = __builtin_amdgcn_mfma_f32_16x16x32_bf16(af, bf, acc[t], 0, 0, 0);
        }
        __syncthreads();
    }

    // Epilogue 1: h = relu(acc + b1) -> Hsm (bf16, A-operand layout for GEMM2)
    // (Hsm aliases the staging buffers; the trailing K-loop barrier guards it.)
    #pragma unroll
    for (int t = 0; t < 16; ++t) {
        int colh = t * 16 + ln;
        float bb = b1[colh];
        #pragma unroll
        for (int i = 0; i < 4; ++i) {
            int row = mw + q * 4 + i;
            float v = acc[t][i] + bb;
            Hsm[row * HPAD + colh] = (bf16)fmaxf(v, 0.0f);
        }
    }
    __syncthreads();

    // GEMM2: X_tile = Hsm @ W2 (K=256, N=32) — 2 n-tiles per wave
    f32x4 acc2[2] = {};
    #pragma unroll
    for (int k0 = 0; k0 < D_HID; k0 += BK) {
        bf16x8 af = *(const bf16x8*)&Hsm[(mw + ln) * HPAD + k0 + q * 8];
        #pragma unroll
        for (int t = 0; t < 2; ++t) {
            bf16x8 bf = *(const bf16x8*)&B2sm[(t * 16 + ln) * HPAD + k0 + q * 8];
            acc2[t] = __builtin_amdgcn_mfma_f32_16x16x32_bf16(af, bf, acc2[t], 0, 0, 0);
        }
    }

    // Epilogue 2: X = acc2 + b2 (fp32)
    #pragma unroll
    for (int t = 0; t < 2; ++t) {
        int c = t * 16 + ln;
        float bb = b2[c];
        #pragma unroll
        for (int i = 0; i < 4; ++i) {
            int row = r0 + mw + q * 4 + i;
            if (row < N) X[row * D_OUT + c] = acc2[t][i] + bb;
        }
    }
}

// ---------------- CSR build: histogram -> scan -> reorder -------------------
__global__ __launch_bounds__(256) void hist_kernel(
    const int* __restrict__ Arow, int* __restrict__ counts, int E)
{
    int e = blockIdx.x * 256 + threadIdx.x;
    if (e < E) atomicAdd(&counts[Arow[e]], 1);
}

__global__ __launch_bounds__(256) void scanA_kernel(
    const int* __restrict__ counts, int* __restrict__ offs,
    int* __restrict__ partials, int N)
{
    __shared__ int lds[256];
    int t = threadIdx.x;
    int base = blockIdx.x * SCAN_SPAN + t * SCAN_VPT;
    int v[SCAN_VPT];
    int tsum = 0;
    #pragma unroll
    for (int j = 0; j < SCAN_VPT; ++j) {
        v[j] = (base + j < N) ? counts[base + j] : 0;
        tsum += v[j];
    }
    lds[t] = tsum;
    __syncthreads();
    for (int d = 1; d < 256; d <<= 1) {
        int x = (t >= d) ? lds[t - d] : 0;
        __syncthreads();
        lds[t] += x;
        __syncthreads();
    }
    int run = lds[t] - tsum;
    #pragma unroll
    for (int j = 0; j < SCAN_VPT; ++j) {
        if (base + j < N) offs[base + j] = run;
        run += v[j];
    }
    if (t == 255) partials[blockIdx.x] = lds[255];
}

__global__ __launch_bounds__(256) void scanB_kernel(int* __restrict__ partials, int nb)
{
    __shared__ int lds[256];
    int t = threadIdx.x;
    int v = (t < nb) ? partials[t] : 0;
    lds[t] = v;
    __syncthreads();
    for (int d = 1; d < 256; d <<= 1) {
        int x = (t >= d) ? lds[t - d] : 0;
        __syncthreads();
        lds[t] += x;
        __syncthreads();
    }
    if (t < nb) partials[t] = lds[t] - v;
}

__global__ __launch_bounds__(256) void scanC_kernel(
    int* __restrict__ offs, const int* __restrict__ partials,
    int* __restrict__ cursor, int N)
{
    int i = blockIdx.x * 256 + threadIdx.x;
    if (i < N) {
        int o = offs[i] + partials[i / SCAN_SPAN];
        offs[i] = o;
        cursor[i] = o;
    }
}

__global__ __launch_bounds__(256) void reorder_kernel(
    const int* __restrict__ Arow, const int* __restrict__ Acol,
    const float* __restrict__ Adata, int* __restrict__ cursor,
    int2* __restrict__ pairs, int E)
{
    int e = blockIdx.x * 256 + threadIdx.x;
    if (e >= E) return;
    int r = Arow[e];
    int p = atomicAdd(&cursor[r], 1);
    int2 pk;
    pk.x = Acol[e];
    pk.y = __float_as_int(Adata[e]);
    pairs[p] = pk;  // single 8B scattered store per edge
}

// ---------------- reduce: one wave per row, 8 edges in flight ---------------
__global__ __launch_bounds__(256) void reduce_kernel(
    const int* __restrict__ offs, const int* __restrict__ counts,
    const int2* __restrict__ pairs, const float* __restrict__ X,
    float* __restrict__ out, int N)
{
    int w    = threadIdx.x >> 6;
    int lane = threadIdx.x & 63;
    int r    = blockIdx.x * 4 + w;
    if (r >= N) return;
    int slot = lane >> 3;    // edge slot 0..7
    int dg   = lane & 7;     // dim group: dims 4*dg..4*dg+3
    int off  = offs[r];
    int deg  = counts[r];
    f32x4 acc = {0.0f, 0.0f, 0.0f, 0.0f};
    for (int i = slot; i < deg; i += 8) {
        int2  pk = pairs[off + i];       // broadcast across the 8 dg lanes
        float a  = __int_as_float(pk.y);
        f32x4 x  = *(const f32x4*)(X + (long)pk.x * D_OUT + dg * 4);
        acc += a * x;
    }
    // butterfly over slots (strides 8,16,32)
    #pragma unroll
    for (int d = 8; d < 64; d <<= 1) {
        acc[0] += __shfl_xor(acc[0], d, 64);
        acc[1] += __shfl_xor(acc[1], d, 64);
        acc[2] += __shfl_xor(acc[2], d, 64);
        acc[3] += __shfl_xor(acc[3], d, 64);
    }
    if (slot == 0) *(f32x4*)(out + (long)r * D_OUT + dg * 4) = acc;
}

// ---------------- fallback scatter (if ws too small) ------------------------
__global__ __launch_bounds__(256) void scatter_kernel(
    const float* __restrict__ Adata, const int* __restrict__ Arow,
    const int* __restrict__ Acol, const float* __restrict__ X,
    float* __restrict__ out, int E)
{
    int idx = blockIdx.x * 256 + threadIdx.x;
    int e = idx >> 3;
    int g = idx & 7;
    if (e >= E) return;
    int   col = Acol[e];
    int   row = Arow[e];
    float a   = Adata[e];
    float4 x = *(const float4*)(X + (long)col * D_OUT + g * 4);
    float* o = out + (long)row * D_OUT + g * 4;
    unsafeAtomicAdd(o + 0, a * x.x);
    unsafeAtomicAdd(o + 1, a * x.y);
    unsafeAtomicAdd(o + 2, a * x.z);
    unsafeAtomicAdd(o + 3, a * x.w);
}

// ---------------- launch ----------------------------------------------------
extern "C" void kernel_launch(void* const* d_in, const int* in_sizes, int n_in,
                              void* d_out, int out_size, void* d_ws, size_t ws_size,
                              hipStream_t stream)
{
    const float* feat  = (const float*)d_in[0];
    const float* Adata = (const float*)d_in[1];
    const float* W1    = (const float*)d_in[2];
    const float* b1    = (const float*)d_in[3];
    const float* W2    = (const float*)d_in[4];
    const float* b2    = (const float*)d_in[5];
    const int*   Arow  = (const int*)d_in[6];
    const int*   Acol  = (const int*)d_in[7];

    const int N = in_sizes[0] / D_IN;
    const int E = in_sizes[1];

    // --- workspace carve-out (256B aligned segments) ---
    char* p = (char*)d_ws;
    auto alloc = [&](size_t bytes) {
        char* q = p;
        p += (bytes + 255) & ~(size_t)255;
        return q;
    };
    float* X       = (float*)alloc((size_t)N * D_OUT * sizeof(float));
    bf16*  W1T     = (bf16*) alloc((size_t)D_IN * D_HID * sizeof(bf16));
    bf16*  W2T     = (bf16*) alloc((size_t)D_HID * D_OUT * sizeof(bf16));
    int*   counts  = (int*)  alloc((size_t)N * sizeof(int));
    int*   offs    = (int*)  alloc((size_t)N * sizeof(int));
    int*   cursor  = (int*)  alloc((size_t)N * sizeof(int));
    int*   partials= (int*)  alloc(256 * sizeof(int));
    int2*  pairs   = (int2*) alloc((size_t)E * sizeof(int2));
    size_t need = (size_t)(p - (char*)d_ws);
    const bool use_csr = (need <= ws_size);

    float* out = (float*)d_out;

    int prep_elems = D_IN * D_HID + D_HID * D_OUT;
    prep_kernel<<<(prep_elems + 255) / 256, 256, 0, stream>>>(W1, W2, W1T, W2T);

    fused_mlp_kernel<<<(N + BM - 1) / BM, 256, 0, stream>>>(
        feat, W1T, W2T, b1, b2, X, N);

    if (use_csr) {
        hipMemsetAsync(counts, 0, (size_t)N * sizeof(int), stream);
        hist_kernel<<<(E + 255) / 256, 256, 0, stream>>>(Arow, counts, E);
        int nb = (N + SCAN_SPAN - 1) / SCAN_SPAN;   // 49 for N=100000 (<=256)
        scanA_kernel<<<nb, 256, 0, stream>>>(counts, offs, partials, N);
        scanB_kernel<<<1, 256, 0, stream>>>(partials, nb);
        scanC_kernel<<<(N + 255) / 256, 256, 0, stream>>>(offs, partials, cursor, N);
        reorder_kernel<<<(E + 255) / 256, 256, 0, stream>>>(
            Arow, Acol, Adata, cursor, pairs, E);
        reduce_kernel<<<(N + 3) / 4, 256, 0, stream>>>(
            offs, counts, pairs, X, out, N);
    } else {
        hipMemsetAsync(out, 0, (size_t)out_size * sizeof(float), stream);
        long scatter_threads = (long)E * 8;
        scatter_kernel<<<(scatter_threads + 255) / 256, 256, 0, stream>>>(
            Adata, Arow, Acol, X, out, E);
    }
}